// Round 1
// baseline (62.407 us; speedup 1.0000x reference)
//
#include <hip/hip_runtime.h>
#include <hip/hip_bf16.h>
#include <math.h>

#define KK 32

// Hardware exp2 (v_exp_f32). Builtin if available, else inline asm.
__device__ __forceinline__ float hw_exp2(float x) {
#if __has_builtin(__builtin_amdgcn_exp2f)
    return __builtin_amdgcn_exp2f(x);
#else
    float r;
    asm("v_exp_f32 %0, %1" : "=v"(r) : "v"(x));
    return r;
#endif
}

// Precompute per-(i,j) quadratic-exponent table:
//   weighted_pdf(x) = exp2(A*x^2 + B*x + C)
//   A = -0.5*log2(e)/sigma^2 ; B = -2*A*mu ; C = A*mu^2 + log2(w * inv_sqrt_2pi / sigma)
// Two folded constants: C1 uses Wk2k1[i][j] (phase 1 / inner),
//                       C0 uses Wk1k0[i][j]*Wk0[j] (phase 2 / mid+final).
__global__ void tt_build_table(const float* __restrict__ Wk0,
                               const float* __restrict__ Wk1k0,
                               const float* __restrict__ Wk2k1,
                               const float* __restrict__ mu,
                               const float* __restrict__ sigma,
                               float4* __restrict__ tab) {
    int idx = blockIdx.x * blockDim.x + threadIdx.x;
    if (idx >= KK * KK) return;
    int j = idx & (KK - 1);
    float m = mu[idx];
    float s = sigma[idx];
    float inv_s = 1.0f / s;
    const float LOG2E = 1.4426950408889634f;
    const float INV_SQRT_2PI = 0.3989422804014327f;
    float A = -0.5f * LOG2E * inv_s * inv_s;
    float B = -2.0f * A * m;
    float Cq = A * m * m;
    float coef = INV_SQRT_2PI * inv_s;
    float c1 = Cq + log2f(Wk2k1[idx] * coef);
    float c0 = Cq + log2f(Wk1k0[idx] * coef * Wk0[j]);
    tab[idx] = make_float4(A, B, c1, c0);
}

__global__ __launch_bounds__(256) void tt_main(const float2* __restrict__ X,
                                               const float4* __restrict__ tab,
                                               float* __restrict__ out,
                                               int ntot) {
    int n = blockIdx.x * 256 + threadIdx.x;
    if (n >= ntot) return;
    float2 x = X[n];

    // ---- Phase 1: inner[k1] = sum_k2 Wk2k1[k2,k1] * pdf(x1; mu[k2,k1], sigma[k2,k1])
    float x1 = x.y;
    float x1s = x1 * x1;
    float inner[KK];
#pragma unroll
    for (int k1 = 0; k1 < KK; ++k1) inner[k1] = 0.0f;

    for (int k2 = 0; k2 < KK; ++k2) {
        const float4* row = tab + k2 * KK;  // uniform address -> s_load
#pragma unroll
        for (int k1 = 0; k1 < KK; ++k1) {
            float4 t = row[k1];
            float e = hw_exp2(__builtin_fmaf(t.x, x1s, __builtin_fmaf(t.y, x1, t.z)));
            inner[k1] += e;
        }
    }

    // ---- Phase 2: lik = sum_{k1,k0} Wk0[k0]*Wk1k0[k1,k0]*pdf(x0;...) * inner[k1]
    float x0 = x.x;
    float x0s = x0 * x0;
    float a0 = 0.0f, a1 = 0.0f, a2 = 0.0f, a3 = 0.0f;

    for (int k0 = 0; k0 < KK; ++k0) {
#pragma unroll
        for (int k1 = 0; k1 < KK; ++k1) {
            float4 t = tab[k1 * KK + k0];  // uniform address -> s_load
            float e = hw_exp2(__builtin_fmaf(t.x, x0s, __builtin_fmaf(t.y, x0, t.w)));
            float term_in = inner[k1];
            // rotate accumulators to break the fma dependency chain
            if ((k1 & 3) == 0)      a0 = __builtin_fmaf(term_in, e, a0);
            else if ((k1 & 3) == 1) a1 = __builtin_fmaf(term_in, e, a1);
            else if ((k1 & 3) == 2) a2 = __builtin_fmaf(term_in, e, a2);
            else                    a3 = __builtin_fmaf(term_in, e, a3);
        }
    }
    float lik = (a0 + a1) + (a2 + a3);
    out[n] = __logf(lik);
}

extern "C" void kernel_launch(void* const* d_in, const int* in_sizes, int n_in,
                              void* d_out, int out_size, void* d_ws, size_t ws_size,
                              hipStream_t stream) {
    const float* X     = (const float*)d_in[0];
    const float* Wk0   = (const float*)d_in[1];
    const float* Wk1k0 = (const float*)d_in[2];
    const float* Wk2k1 = (const float*)d_in[3];
    const float* mu    = (const float*)d_in[4];
    const float* sigma = (const float*)d_in[5];
    float* out = (float*)d_out;
    float4* tab = (float4*)d_ws;  // 1024 * 16B = 16 KB

    int ntot = in_sizes[0] / 2;  // N = 131072

    tt_build_table<<<(KK * KK + 255) / 256, 256, 0, stream>>>(Wk0, Wk1k0, Wk2k1, mu, sigma, tab);
    tt_main<<<(ntot + 255) / 256, 256, 0, stream>>>((const float2*)X, tab, out, ntot);
}